// Round 5
// baseline (200.847 us; speedup 1.0000x reference)
//
#include <hip/hip_runtime.h>
#include <hip/hip_bf16.h>
#include <math.h>

#define NN 8192
#define QSCALE (0.125f * 1.44269504088896f)   // fold 0.125 and log2(e) into Q
#define OSZ (8192*64)

typedef __attribute__((ext_vector_type(8))) short short8;
typedef __attribute__((ext_vector_type(16))) float f32x16;
typedef __attribute__((ext_vector_type(4))) unsigned uint4e;

union W4 { uint4e u4; unsigned u[4]; short8 v; };

__device__ inline unsigned short f2bf(float x) {
  union { float f; unsigned u; } t; t.f = x;
  unsigned r = t.u + 0x7fffu + ((t.u >> 16) & 1u);
  return (unsigned short)(r >> 16);
}
__device__ inline unsigned cvtpk(float lo, float hi) {
  unsigned r;
  asm("v_cvt_pk_bf16_f32 %0, %1, %2" : "=v"(r) : "v"(lo), "v"(hi));
  return r;
}

// ---------------------------------------------------------------------------
// Kernel 1: Q/K/V/H pre-pack.
//  QP[c8][i][e] = Q[i][c8*8+e]*QSCALE ; KP same for K
//  VP[j8][d][e] = V[j8*8+e][d] ; HP same for H
// ---------------------------------------------------------------------------
__global__ __launch_bounds__(256) void qkv_kernel(
    const float* __restrict__ X, const float* __restrict__ H,
    const float* __restrict__ Qw, const float* __restrict__ Qb,
    const float* __restrict__ Kw, const float* __restrict__ Kb,
    const float* __restrict__ Vw, const float* __restrict__ Vb,
    const float* __restrict__ bng, const float* __restrict__ bnb,
    const float* __restrict__ bnm, const float* __restrict__ bnv,
    unsigned short* __restrict__ QP, unsigned short* __restrict__ KP,
    unsigned short* __restrict__ VP, unsigned short* __restrict__ HP)
{
  int wid = (blockIdx.x * blockDim.x + threadIdx.x) >> 6; // 0..2047
  int d = threadIdx.x & 63;
  float4 w[16];

  for (int fq = 0; fq < 16; fq++) w[fq] = *(const float4*)(Qw + d*64 + fq*4);
  for (int rr = 0; rr < 4; rr++) {
    int r = wid*4 + rr;
    float a = Qb[d];
    for (int fq = 0; fq < 16; fq++) {
      float4 xv = *(const float4*)(X + r*64 + fq*4);
      a += w[fq].x*xv.x + w[fq].y*xv.y + w[fq].z*xv.z + w[fq].w*xv.w;
    }
    float s = a;
    for (int off = 32; off; off >>= 1) s += __shfl_xor(s, off);
    float mean = s * (1.f/64.f);
    float c = a - mean;
    float s2 = c*c;
    for (int off = 32; off; off >>= 1) s2 += __shfl_xor(s2, off);
    float q = c * rsqrtf(s2*(1.f/64.f) + 1e-5f);
    QP[(d>>3)*65536 + r*8 + (d&7)] = f2bf(q * QSCALE);
  }
  for (int fq = 0; fq < 16; fq++) w[fq] = *(const float4*)(Kw + d*64 + fq*4);
  for (int rr = 0; rr < 4; rr++) {
    int r = wid*4 + rr;
    float a = Kb[d];
    for (int fq = 0; fq < 16; fq++) {
      float4 hv = *(const float4*)(H + r*64 + fq*4);
      a += w[fq].x*hv.x + w[fq].y*hv.y + w[fq].z*hv.z + w[fq].w*hv.w;
    }
    float s = a;
    for (int off = 32; off; off >>= 1) s += __shfl_xor(s, off);
    float mean = s * (1.f/64.f);
    float c = a - mean;
    float s2 = c*c;
    for (int off = 32; off; off >>= 1) s2 += __shfl_xor(s2, off);
    float k = c * rsqrtf(s2*(1.f/64.f) + 1e-5f);
    KP[(d>>3)*65536 + r*8 + (d&7)] = f2bf(k);
  }
  for (int fq = 0; fq < 16; fq++) w[fq] = *(const float4*)(Vw + d*64 + fq*4);
  float bscale = rsqrtf(bnv[d] + 1e-5f) * bng[d];
  for (int rr = 0; rr < 4; rr++) {
    int r = wid*4 + rr;
    float a = Vb[d];
    for (int fq = 0; fq < 16; fq++) {
      float4 hv = *(const float4*)(H + r*64 + fq*4);
      a += w[fq].x*hv.x + w[fq].y*hv.y + w[fq].z*hv.z + w[fq].w*hv.w;
    }
    float v = (a - bnm[d]) * bscale + bnb[d];
    VP[(r>>3)*512 + d*8 + (r&7)] = f2bf(v);
    HP[(r>>3)*512 + d*8 + (r&7)] = f2bf(H[r*64 + d]);
  }
}

// ---------------------------------------------------------------------------
// pass 1: per-column sums of exp2(s*M)  AND  M -> MT4 transpose-pack (bf16).
// 1-deep register prefetch of the 16 M row-dwords (32 outstanding/wave).
// ---------------------------------------------------------------------------
__global__ __launch_bounds__(256) void pass1_kernel(
    const float* __restrict__ M, const unsigned short* __restrict__ QP,
    const unsigned short* __restrict__ KP, unsigned* __restrict__ MT4,
    float* __restrict__ pd)
{
  __shared__ __align__(16) float ld[4][32*34];
  int tid = threadIdx.x;
  int wj = (blockIdx.x * blockDim.x + tid) >> 6;  // 0..8191
  int lane = tid & 63;
  int wv = tid >> 6;
  int l31 = lane & 31, h = lane >> 5;
  int jb = wj & 255, slice = wj >> 8;             // 256 jb x 32 slices
  int j = jb*32 + l31;
  float* lds = ld[wv];

  short8 kb[4];
  for (int m = 0; m < 4; m++)
    kb[m] = *(const short8*)(KP + (2*m + h)*65536 + j*8);

  float Mv[16];
  {
    int i0 = slice*8*32;
#pragma unroll
    for (int r = 0; r < 16; r++) {
      int ir = (r&3) + 8*(r>>2) + 4*h;
      Mv[r] = __builtin_nontemporal_load(M + (size_t)(i0 + ir)*NN + j);
    }
  }

  float d0 = 0.f, d1 = 0.f, d2 = 0.f, d3 = 0.f;
  for (int t = 0; t < 8; t++) {
    int i0 = (slice*8 + t) * 32;
    // ---- prefetch next i-slice of M ----
    float Mn[16];
    if (t < 7) {
      int i1 = i0 + 32;
#pragma unroll
      for (int r = 0; r < 16; r++) {
        int ir = (r&3) + 8*(r>>2) + 4*h;
        Mn[r] = __builtin_nontemporal_load(M + (size_t)(i1 + ir)*NN + j);
      }
    }

    f32x16 acc;
    for (int r = 0; r < 16; r++) acc[r] = 0.f;
    for (int m = 0; m < 4; m++) {
      short8 qa = *(const short8*)(QP + (2*m + h)*65536 + (size_t)(i0 + l31)*8);
      acc = __builtin_amdgcn_mfma_f32_32x32x16_bf16(qa, kb[m], acc, 0, 0, 0);
    }

#pragma unroll
    for (int r = 0; r < 16; r++) {
      int ir = (r&3) + 8*(r>>2) + 4*h;
      lds[ir*34 + l31] = Mv[r];
    }
    d0 += exp2f(acc[0]*Mv[0]) + exp2f(acc[4]*Mv[4]) + exp2f(acc[8]*Mv[8])   + exp2f(acc[12]*Mv[12]);
    d1 += exp2f(acc[1]*Mv[1]) + exp2f(acc[5]*Mv[5]) + exp2f(acc[9]*Mv[9])   + exp2f(acc[13]*Mv[13]);
    d2 += exp2f(acc[2]*Mv[2]) + exp2f(acc[6]*Mv[6]) + exp2f(acc[10]*Mv[10]) + exp2f(acc[14]*Mv[14]);
    d3 += exp2f(acc[3]*Mv[3]) + exp2f(acc[7]*Mv[7]) + exp2f(acc[11]*Mv[11]) + exp2f(acc[15]*Mv[15]);

    asm volatile("s_waitcnt lgkmcnt(0)" ::: "memory");  // wave-local transpose
    int ii = l31;
    int i_g = i0 + ii;
#pragma unroll
    for (int qq = 0; qq < 2; qq++) {
      int q = 2*h + qq;                     // h=0 -> q 0,1 ; h=1 -> q 2,3
      unsigned w0, w1, w2, w3;
      {
        float2 a2 = *(const float2*)(&lds[ii*34 + 8*q + 0]);
        float2 b2 = *(const float2*)(&lds[ii*34 + 8*q + 2]);
        float2 c2 = *(const float2*)(&lds[ii*34 + 8*q + 4]);
        float2 e2 = *(const float2*)(&lds[ii*34 + 8*q + 6]);
        w0 = cvtpk(a2.x, a2.y); w1 = cvtpk(b2.x, b2.y);
        w2 = cvtpk(c2.x, c2.y); w3 = cvtpk(e2.x, e2.y);
      }
      uint4e ww = {w0, w1, w2, w3};
      *(uint4e*)(MT4 + (size_t)(jb*4 + q)*32768 + (size_t)i_g*4) = ww;
    }
    if (t < 7) {
#pragma unroll
      for (int r = 0; r < 16; r++) Mv[r] = Mn[r];
    }
  }
  float drun = (d0 + d1) + (d2 + d3);
  drun += __shfl_xor(drun, 32);
  if (lane < 32) pd[(size_t)slice*NN + j] = drun;
}

// ---------------------------------------------------------------------------
// combine: cc[j] = log2(10 * D_j)
// ---------------------------------------------------------------------------
__global__ __launch_bounds__(256) void combine_kernel(
    const float* __restrict__ pd, float* __restrict__ colcc)
{
  int j = blockIdx.x * blockDim.x + threadIdx.x;
  float Dv = 0.f;
  for (int s = 0; s < 32; s++) Dv += pd[(size_t)s*NN + j];
  colcc[j] = log2f(Dv * 10.f);
}

// ---------------------------------------------------------------------------
// pass 2: partial out = alpha*A@V + M@H per j-slice. 1-deep prefetch of
// MT4 + KP fragments; E-words obtained from neighbor half via
// v_permlane32_swap_b32 on copies of A0/A1 (saves 2 loads/iter).
// ---------------------------------------------------------------------------
__global__ __launch_bounds__(256) void pass2_kernel(
    const unsigned* __restrict__ MT4, const unsigned short* __restrict__ QP,
    const unsigned short* __restrict__ KP, const unsigned short* __restrict__ VP,
    const unsigned short* __restrict__ HP, const float* __restrict__ colcc,
    float* __restrict__ opart)
{
  __shared__ __align__(16) float cls[512];

  int iblk = blockIdx.x >> 4, slice = blockIdx.x & 15;
  int i0 = iblk * 64;
  int tid = threadIdx.x;
  int lane = tid & 63, wid = tid >> 6;
  int l31 = lane & 31, h = lane >> 5;
  int iq = wid & 1, dh = wid >> 1;
  int row = iq*32 + l31;
  int i_g = i0 + row;

  short8 qb[4];
  for (int m = 0; m < 4; m++)
    qb[m] = *(const short8*)(QP + (2*m + h)*65536 + (size_t)i_g*8);

  cls[tid]       = colcc[slice*512 + tid];
  cls[tid + 256] = colcc[slice*512 + 256 + tid];
  __syncthreads();

  f32x16 oacc;
  for (int r = 0; r < 16; r++) oacc[r] = 0.f;

  const unsigned* mbase = MT4 + (size_t)i_g*4;

  // ---- prefetch t=0 ----
  W4 A0c, A1c; short8 kac[4];
  {
    int jt = slice*512, jtb = jt >> 3;
    A0c.u4 = *(const uint4e*)(mbase + (size_t)(jtb + h)*32768);
    A1c.u4 = *(const uint4e*)(mbase + (size_t)(jtb + 2 + h)*32768);
    for (int m = 0; m < 4; m++)
      kac[m] = *(const short8*)(KP + (2*m + h)*65536 + (size_t)(jt + l31)*8);
  }

  for (int t = 0; t < 16; t++) {
    int jt = slice*512 + t*32;

    // ---- prefetch t+1 ----
    W4 A0n, A1n; short8 kan[4];
    if (t < 15) {
      int jn = jt + 32, jnb = jn >> 3;
      A0n.u4 = *(const uint4e*)(mbase + (size_t)(jnb + h)*32768);
      A1n.u4 = *(const uint4e*)(mbase + (size_t)(jnb + 2 + h)*32768);
      for (int m = 0; m < 4; m++)
        kan[m] = *(const short8*)(KP + (2*m + h)*65536 + (size_t)(jn + l31)*8);
    }

    // ---- V/H B-frags (L2-resident) ----
    int j8 = jt >> 3;
    const unsigned short* vbase = VP + (size_t)j8*512 + (dh*32 + l31)*8;
    const unsigned short* hbase = HP + (size_t)j8*512 + (dh*32 + l31)*8;
    short8 vb1 = *(const short8*)(vbase + h*512);
    short8 vb2 = *(const short8*)(vbase + (2 + h)*512);
    short8 hb1 = *(const short8*)(hbase + h*512);
    short8 hb2 = *(const short8*)(hbase + (2 + h)*512);

    // ---- s'^T = K x (Q*QSCALE)^T : lane l31 = i, regs = j ----
    f32x16 sacc;
    for (int r = 0; r < 16; r++) sacc[r] = 0.f;
    for (int m = 0; m < 4; m++)
      sacc = __builtin_amdgcn_mfma_f32_32x32x16_bf16(kac[m], qb[m], sacc, 0, 0, 0);

    // ---- mw words: cross-half exchange instead of E loads ----
    unsigned mw0 = A0c.u[0], mw2 = A0c.u[2];
    unsigned mw1 = A0c.u[1], mw3 = A0c.u[3];
    unsigned mw4 = A1c.u[0], mw6 = A1c.u[2];
    unsigned mw5 = A1c.u[1], mw7 = A1c.u[3];
    asm volatile("v_permlane32_swap_b32 %0, %1" : "+v"(mw0), "+v"(mw2));
    asm volatile("v_permlane32_swap_b32 %0, %1" : "+v"(mw1), "+v"(mw3));
    asm volatile("v_permlane32_swap_b32 %0, %1" : "+v"(mw4), "+v"(mw6));
    asm volatile("v_permlane32_swap_b32 %0, %1" : "+v"(mw5), "+v"(mw7));
    unsigned mw[8] = {mw0, mw1, mw2, mw3, mw4, mw5, mw6, mw7};

    // ---- p = exp2(s*M - cc) ----
    float p[16];
#pragma unroll
    for (int q = 0; q < 4; q++) {
      float4 cc = *(const float4*)(&cls[t*32 + 8*q + 4*h]);
      unsigned wa = mw[2*q], wb = mw[2*q + 1];
      float m0 = __uint_as_float(wa << 16);
      float m1 = __uint_as_float(wa & 0xffff0000u);
      float m2 = __uint_as_float(wb << 16);
      float m3 = __uint_as_float(wb & 0xffff0000u);
      p[4*q+0] = exp2f(fmaf(sacc[4*q+0], m0, -cc.x));
      p[4*q+1] = exp2f(fmaf(sacc[4*q+1], m1, -cc.y));
      p[4*q+2] = exp2f(fmaf(sacc[4*q+2], m2, -cc.z));
      p[4*q+3] = exp2f(fmaf(sacc[4*q+3], m3, -cc.w));
    }
    unsigned pu[8];
#pragma unroll
    for (int k = 0; k < 8; k++) pu[k] = cvtpk(p[2*k], p[2*k+1]);

    asm volatile("v_permlane32_swap_b32 %0, %1" : "+v"(pu[0]), "+v"(pu[2]));
    asm volatile("v_permlane32_swap_b32 %0, %1" : "+v"(pu[1]), "+v"(pu[3]));
    asm volatile("v_permlane32_swap_b32 %0, %1" : "+v"(pu[4]), "+v"(pu[6]));
    asm volatile("v_permlane32_swap_b32 %0, %1" : "+v"(pu[5]), "+v"(pu[7]));

    W4 PA0, PA1;
    PA0.u[0] = pu[0]; PA0.u[1] = pu[1]; PA0.u[2] = pu[2]; PA0.u[3] = pu[3];
    PA1.u[0] = pu[4]; PA1.u[1] = pu[5]; PA1.u[2] = pu[6]; PA1.u[3] = pu[7];

    oacc = __builtin_amdgcn_mfma_f32_32x32x16_bf16(PA0.v, vb1, oacc, 0, 0, 0);
    oacc = __builtin_amdgcn_mfma_f32_32x32x16_bf16(PA1.v, vb2, oacc, 0, 0, 0);
    oacc = __builtin_amdgcn_mfma_f32_32x32x16_bf16(A0c.v, hb1, oacc, 0, 0, 0);
    oacc = __builtin_amdgcn_mfma_f32_32x32x16_bf16(A1c.v, hb2, oacc, 0, 0, 0);

    if (t < 15) {
      A0c = A1n; // placeholder to avoid copy-order bug? no -- see below
    }
    // correct rotation (overwrite after use):
    if (t < 15) {
      A0c = A0n; A1c = A1n;
      for (int m = 0; m < 4; m++) kac[m] = kan[m];
    }
  }

  float* obase = opart + (size_t)slice*OSZ;
#pragma unroll
  for (int r = 0; r < 16; r++) {
    int orow = i0 + iq*32 + (r&3) + 8*(r>>2) + 4*h;
    int ocol = dh*32 + l31;
    obase[(size_t)orow*64 + ocol] = oacc[r];
  }
}

// ---------------------------------------------------------------------------
// reduce: out = sum over 16 slices of opart  (float4, fully coalesced)
// ---------------------------------------------------------------------------
__global__ __launch_bounds__(256) void reduce_kernel(
    const float* __restrict__ opart, float* __restrict__ out)
{
  int e4 = blockIdx.x * blockDim.x + threadIdx.x;   // 0..131071
  const float4* p = (const float4*)opart;
  float4 a = p[e4];
#pragma unroll
  for (int s = 1; s < 16; s++) {
    float4 b = p[(size_t)s*(OSZ/4) + e4];
    a.x += b.x; a.y += b.y; a.z += b.z; a.w += b.w;
  }
  ((float4*)out)[e4] = a;
}

// ---------------------------------------------------------------------------
extern "C" void kernel_launch(void* const* d_in, const int* in_sizes, int n_in,
                              void* d_out, int out_size, void* d_ws, size_t ws_size,
                              hipStream_t stream) {
  const float* X   = (const float*)d_in[0];
  const float* H   = (const float*)d_in[1];
  const float* M   = (const float*)d_in[2];
  const float* Qw  = (const float*)d_in[3];
  const float* Qb  = (const float*)d_in[4];
  const float* Kw  = (const float*)d_in[5];
  const float* Kb  = (const float*)d_in[6];
  const float* Vw  = (const float*)d_in[7];
  const float* Vb  = (const float*)d_in[8];
  const float* bng = (const float*)d_in[9];
  const float* bnb = (const float*)d_in[10];
  const float* bnm = (const float*)d_in[11];
  const float* bnv = (const float*)d_in[12];
  float* out = (float*)d_out;

  char* ws = (char*)d_ws;
  const size_t MB = 1024*1024;
  unsigned* MT4       = (unsigned*)(ws);                 // 128 MB
  unsigned short* QP  = (unsigned short*)(ws + 128*MB);  // 1 MB
  unsigned short* KP  = (unsigned short*)(ws + 129*MB);
  unsigned short* VP  = (unsigned short*)(ws + 130*MB);
  unsigned short* HP  = (unsigned short*)(ws + 131*MB);
  float* pd           = (float*)(ws + 132*MB);           // 1 MB
  float* colcc        = (float*)(ws + 133*MB);           // 32 KB
  float* opart        = (float*)(ws + 134*MB);           // 32 MB

  qkv_kernel<<<512, 256, 0, stream>>>(X, H, Qw, Qb, Kw, Kb, Vw, Vb,
                                      bng, bnb, bnm, bnv, QP, KP, VP, HP);
  pass1_kernel<<<2048, 256, 0, stream>>>(M, QP, KP, MT4, pd);
  combine_kernel<<<32, 256, 0, stream>>>(pd, colcc);
  pass2_kernel<<<2048, 256, 0, stream>>>(MT4, QP, KP, VP, HP, colcc, opart);
  reduce_kernel<<<512, 256, 0, stream>>>(opart, out);
}

// Round 6
// 195.423 us; speedup vs baseline: 1.0278x; 1.0278x over previous
//
#include <hip/hip_runtime.h>
#include <hip/hip_bf16.h>
#include <math.h>

#define NN 8192
#define QSCALE (0.125f * 1.44269504088896f)   // fold 0.125 and log2(e) into Q
#define OSZ (8192*64)

typedef __attribute__((ext_vector_type(8))) short short8;
typedef __attribute__((ext_vector_type(16))) float f32x16;
typedef __attribute__((ext_vector_type(4))) unsigned uint4e;

union W4 { uint4e u4; unsigned u[4]; short8 v; };

__device__ inline unsigned short f2bf(float x) {
  union { float f; unsigned u; } t; t.f = x;
  unsigned r = t.u + 0x7fffu + ((t.u >> 16) & 1u);
  return (unsigned short)(r >> 16);
}
__device__ inline unsigned cvtpk(float lo, float hi) {
  unsigned r;
  asm("v_cvt_pk_bf16_f32 %0, %1, %2" : "=v"(r) : "v"(lo), "v"(hi));
  return r;
}
// raw HW exp2 (args bounded well inside range; no denormal concerns)
__device__ inline float fexp2(float x) {
  float r;
  asm("v_exp_f32 %0, %1" : "=v"(r) : "v"(x));
  return r;
}

// ---------------------------------------------------------------------------
// Kernel 1: Q/K/V/H pre-pack.
//  QP[c8][i][e] = Q[i][c8*8+e]*QSCALE ; KP same for K
//  VP[j8][d][e] = V[j8*8+e][d] ; HP same for H
// ---------------------------------------------------------------------------
__global__ __launch_bounds__(256) void qkv_kernel(
    const float* __restrict__ X, const float* __restrict__ H,
    const float* __restrict__ Qw, const float* __restrict__ Qb,
    const float* __restrict__ Kw, const float* __restrict__ Kb,
    const float* __restrict__ Vw, const float* __restrict__ Vb,
    const float* __restrict__ bng, const float* __restrict__ bnb,
    const float* __restrict__ bnm, const float* __restrict__ bnv,
    unsigned short* __restrict__ QP, unsigned short* __restrict__ KP,
    unsigned short* __restrict__ VP, unsigned short* __restrict__ HP)
{
  int wid = (blockIdx.x * blockDim.x + threadIdx.x) >> 6; // 0..2047
  int d = threadIdx.x & 63;
  float4 w[16];

  for (int fq = 0; fq < 16; fq++) w[fq] = *(const float4*)(Qw + d*64 + fq*4);
  for (int rr = 0; rr < 4; rr++) {
    int r = wid*4 + rr;
    float a = Qb[d];
    for (int fq = 0; fq < 16; fq++) {
      float4 xv = *(const float4*)(X + r*64 + fq*4);
      a += w[fq].x*xv.x + w[fq].y*xv.y + w[fq].z*xv.z + w[fq].w*xv.w;
    }
    float s = a;
    for (int off = 32; off; off >>= 1) s += __shfl_xor(s, off);
    float mean = s * (1.f/64.f);
    float c = a - mean;
    float s2 = c*c;
    for (int off = 32; off; off >>= 1) s2 += __shfl_xor(s2, off);
    float q = c * rsqrtf(s2*(1.f/64.f) + 1e-5f);
    QP[(d>>3)*65536 + r*8 + (d&7)] = f2bf(q * QSCALE);
  }
  for (int fq = 0; fq < 16; fq++) w[fq] = *(const float4*)(Kw + d*64 + fq*4);
  for (int rr = 0; rr < 4; rr++) {
    int r = wid*4 + rr;
    float a = Kb[d];
    for (int fq = 0; fq < 16; fq++) {
      float4 hv = *(const float4*)(H + r*64 + fq*4);
      a += w[fq].x*hv.x + w[fq].y*hv.y + w[fq].z*hv.z + w[fq].w*hv.w;
    }
    float s = a;
    for (int off = 32; off; off >>= 1) s += __shfl_xor(s, off);
    float mean = s * (1.f/64.f);
    float c = a - mean;
    float s2 = c*c;
    for (int off = 32; off; off >>= 1) s2 += __shfl_xor(s2, off);
    float k = c * rsqrtf(s2*(1.f/64.f) + 1e-5f);
    KP[(d>>3)*65536 + r*8 + (d&7)] = f2bf(k);
  }
  for (int fq = 0; fq < 16; fq++) w[fq] = *(const float4*)(Vw + d*64 + fq*4);
  float bscale = rsqrtf(bnv[d] + 1e-5f) * bng[d];
  for (int rr = 0; rr < 4; rr++) {
    int r = wid*4 + rr;
    float a = Vb[d];
    for (int fq = 0; fq < 16; fq++) {
      float4 hv = *(const float4*)(H + r*64 + fq*4);
      a += w[fq].x*hv.x + w[fq].y*hv.y + w[fq].z*hv.z + w[fq].w*hv.w;
    }
    float v = (a - bnm[d]) * bscale + bnb[d];
    VP[(r>>3)*512 + d*8 + (r&7)] = f2bf(v);
    HP[(r>>3)*512 + d*8 + (r&7)] = f2bf(H[r*64 + d]);
  }
}

// ---------------------------------------------------------------------------
// pass 1: per-column sums of exp2(s*M)  AND  M -> MT4 transpose-pack (bf16).
// WG (4 waves) = (jb0..jb0+3) x slice. Per t-iter the WG cooperatively
// stages a 32-row x 128-col f32 M tile into LDS with float4 loads that are
// 1KB-contiguous per instruction (fixes 128B-granule HBM scatter).
// Waves consume their 32-col subtile (b32, conflict-free) and produce the
// MT4 transpose readback directly from the staged tile (b64).
// Double-buffered; one __syncthreads per iter.
// ---------------------------------------------------------------------------
#define MSTRIDE 132   // 128 + 4 pad floats: 16B-aligned rows, bank shift 4/row

__global__ __launch_bounds__(256) void pass1_kernel(
    const float* __restrict__ M, const unsigned short* __restrict__ QP,
    const unsigned short* __restrict__ KP, unsigned* __restrict__ MT4,
    float* __restrict__ pd)
{
  __shared__ __align__(16) float mstage[2][32*MSTRIDE];
  int tid = threadIdx.x;
  int lane = tid & 63;
  int wv = tid >> 6;
  int l31 = lane & 31, h = lane >> 5;
  int jb0 = (blockIdx.x*4) & 255;        // WG j-base (4 jb blocks)
  int slice = blockIdx.x >> 6;           // 0..31
  int jb = jb0 + wv;
  int j = jb*32 + l31;

  short8 kb[4];
  for (int m = 0; m < 4; m++)
    kb[m] = *(const short8*)(KP + (2*m + h)*65536 + j*8);

  // staging: 4 float4 per thread; n = rr*256+tid -> row n>>5, col4 n&31
  const float* msrc = M + (size_t)(slice*256)*NN + jb0*32;
  int srow[4], scol[4];
#pragma unroll
  for (int rr = 0; rr < 4; rr++) {
    int n = rr*256 + tid;
    srow[rr] = n >> 5; scol[rr] = (n & 31) * 4;
  }

#pragma unroll
  for (int rr = 0; rr < 4; rr++) {
    float4 v = *(const float4*)(msrc + (size_t)srow[rr]*NN + scol[rr]);
    *(float4*)(&mstage[0][srow[rr]*MSTRIDE + scol[rr]]) = v;
  }
  __syncthreads();

  float d0 = 0.f, d1 = 0.f, d2 = 0.f, d3 = 0.f;
  for (int t = 0; t < 8; t++) {
    int i0 = (slice*8 + t) * 32;
    // ---- stage t+1 into the other buffer ----
    if (t < 7) {
      const float* src = msrc + (size_t)(t+1)*32*NN;
      float* dst = mstage[(t+1) & 1];
#pragma unroll
      for (int rr = 0; rr < 4; rr++) {
        float4 v = *(const float4*)(src + (size_t)srow[rr]*NN + scol[rr]);
        *(float4*)(&dst[srow[rr]*MSTRIDE + scol[rr]]) = v;
      }
    }
    const float* mb = mstage[t & 1];

    // ---- QK^T mfma ----
    f32x16 acc;
    for (int r = 0; r < 16; r++) acc[r] = 0.f;
    for (int m = 0; m < 4; m++) {
      short8 qa = *(const short8*)(QP + (2*m + h)*65536 + (size_t)(i0 + l31)*8);
      acc = __builtin_amdgcn_mfma_f32_32x32x16_bf16(qa, kb[m], acc, 0, 0, 0);
    }

    // ---- Mv from LDS (b32, conflict-free), exp, colsum partials ----
    float Mv[16];
#pragma unroll
    for (int r = 0; r < 16; r++) {
      int ir = (r&3) + 8*(r>>2) + 4*h;
      Mv[r] = mb[ir*MSTRIDE + wv*32 + l31];
    }
    d0 += fexp2(acc[0]*Mv[0]) + fexp2(acc[4]*Mv[4]) + fexp2(acc[8]*Mv[8])   + fexp2(acc[12]*Mv[12]);
    d1 += fexp2(acc[1]*Mv[1]) + fexp2(acc[5]*Mv[5]) + fexp2(acc[9]*Mv[9])   + fexp2(acc[13]*Mv[13]);
    d2 += fexp2(acc[2]*Mv[2]) + fexp2(acc[6]*Mv[6]) + fexp2(acc[10]*Mv[10]) + fexp2(acc[14]*Mv[14]);
    d3 += fexp2(acc[3]*Mv[3]) + fexp2(acc[7]*Mv[7]) + fexp2(acc[11]*Mv[11]) + fexp2(acc[15]*Mv[15]);

    // ---- MT4 transpose readback straight from staged tile ----
    int ii = l31;
    int i_g = i0 + ii;
#pragma unroll
    for (int qq = 0; qq < 2; qq++) {
      int q = 2*h + qq;                 // h=0 -> q 0,1 ; h=1 -> q 2,3
      const float* rbase = &mb[ii*MSTRIDE + wv*32 + 8*q];
      float2 a2 = *(const float2*)(rbase + 0);
      float2 b2 = *(const float2*)(rbase + 2);
      float2 c2 = *(const float2*)(rbase + 4);
      float2 e2 = *(const float2*)(rbase + 6);
      uint4e ww = {cvtpk(a2.x, a2.y), cvtpk(b2.x, b2.y),
                   cvtpk(c2.x, c2.y), cvtpk(e2.x, e2.y)};
      *(uint4e*)(MT4 + (size_t)(jb*4 + q)*32768 + (size_t)i_g*4) = ww;
    }
    __syncthreads();
  }
  float drun = (d0 + d1) + (d2 + d3);
  drun += __shfl_xor(drun, 32);
  if (lane < 32) pd[(size_t)slice*NN + j] = drun;
}

// ---------------------------------------------------------------------------
// combine: cc[j] = log2(10 * D_j)
// ---------------------------------------------------------------------------
__global__ __launch_bounds__(256) void combine_kernel(
    const float* __restrict__ pd, float* __restrict__ colcc)
{
  int j = blockIdx.x * blockDim.x + threadIdx.x;
  float Dv = 0.f;
  for (int s = 0; s < 32; s++) Dv += pd[(size_t)s*NN + j];
  colcc[j] = log2f(Dv * 10.f);
}

// ---------------------------------------------------------------------------
// pass 2: partial out = alpha*A@V + M@H per j-slice. 1-deep prefetch of
// MT4 + KP fragments; E-words from neighbor half via v_permlane32_swap_b32.
// ---------------------------------------------------------------------------
__global__ __launch_bounds__(256) void pass2_kernel(
    const unsigned* __restrict__ MT4, const unsigned short* __restrict__ QP,
    const unsigned short* __restrict__ KP, const unsigned short* __restrict__ VP,
    const unsigned short* __restrict__ HP, const float* __restrict__ colcc,
    float* __restrict__ opart)
{
  __shared__ __align__(16) float cls[512];

  int iblk = blockIdx.x >> 4, slice = blockIdx.x & 15;
  int i0 = iblk * 64;
  int tid = threadIdx.x;
  int lane = tid & 63, wid = tid >> 6;
  int l31 = lane & 31, h = lane >> 5;
  int iq = wid & 1, dh = wid >> 1;
  int row = iq*32 + l31;
  int i_g = i0 + row;

  short8 qb[4];
  for (int m = 0; m < 4; m++)
    qb[m] = *(const short8*)(QP + (2*m + h)*65536 + (size_t)i_g*8);

  cls[tid]       = colcc[slice*512 + tid];
  cls[tid + 256] = colcc[slice*512 + 256 + tid];
  __syncthreads();

  f32x16 oacc;
  for (int r = 0; r < 16; r++) oacc[r] = 0.f;

  const unsigned* mbase = MT4 + (size_t)i_g*4;

  // ---- prefetch t=0 ----
  W4 A0c, A1c; short8 kac[4];
  {
    int jt = slice*512, jtb = jt >> 3;
    A0c.u4 = *(const uint4e*)(mbase + (size_t)(jtb + h)*32768);
    A1c.u4 = *(const uint4e*)(mbase + (size_t)(jtb + 2 + h)*32768);
    for (int m = 0; m < 4; m++)
      kac[m] = *(const short8*)(KP + (2*m + h)*65536 + (size_t)(jt + l31)*8);
  }

  for (int t = 0; t < 16; t++) {
    int jt = slice*512 + t*32;

    // ---- prefetch t+1 ----
    W4 A0n, A1n; short8 kan[4];
    if (t < 15) {
      int jn = jt + 32, jnb = jn >> 3;
      A0n.u4 = *(const uint4e*)(mbase + (size_t)(jnb + h)*32768);
      A1n.u4 = *(const uint4e*)(mbase + (size_t)(jnb + 2 + h)*32768);
      for (int m = 0; m < 4; m++)
        kan[m] = *(const short8*)(KP + (2*m + h)*65536 + (size_t)(jn + l31)*8);
    }

    // ---- V/H B-frags (L2-resident) ----
    int j8 = jt >> 3;
    const unsigned short* vbase = VP + (size_t)j8*512 + (dh*32 + l31)*8;
    const unsigned short* hbase = HP + (size_t)j8*512 + (dh*32 + l31)*8;
    short8 vb1 = *(const short8*)(vbase + h*512);
    short8 vb2 = *(const short8*)(vbase + (2 + h)*512);
    short8 hb1 = *(const short8*)(hbase + h*512);
    short8 hb2 = *(const short8*)(hbase + (2 + h)*512);

    // ---- s'^T = K x (Q*QSCALE)^T : lane l31 = i, regs = j ----
    f32x16 sacc;
    for (int r = 0; r < 16; r++) sacc[r] = 0.f;
    for (int m = 0; m < 4; m++)
      sacc = __builtin_amdgcn_mfma_f32_32x32x16_bf16(kac[m], qb[m], sacc, 0, 0, 0);

    // ---- mw words: cross-half exchange instead of extra loads ----
    unsigned mw0 = A0c.u[0], mw2 = A0c.u[2];
    unsigned mw1 = A0c.u[1], mw3 = A0c.u[3];
    unsigned mw4 = A1c.u[0], mw6 = A1c.u[2];
    unsigned mw5 = A1c.u[1], mw7 = A1c.u[3];
    asm volatile("v_permlane32_swap_b32 %0, %1" : "+v"(mw0), "+v"(mw2));
    asm volatile("v_permlane32_swap_b32 %0, %1" : "+v"(mw1), "+v"(mw3));
    asm volatile("v_permlane32_swap_b32 %0, %1" : "+v"(mw4), "+v"(mw6));
    asm volatile("v_permlane32_swap_b32 %0, %1" : "+v"(mw5), "+v"(mw7));
    unsigned mw[8] = {mw0, mw1, mw2, mw3, mw4, mw5, mw6, mw7};

    // ---- p = exp2(s*M - cc) ----
    float p[16];
#pragma unroll
    for (int q = 0; q < 4; q++) {
      float4 cc = *(const float4*)(&cls[t*32 + 8*q + 4*h]);
      unsigned wa = mw[2*q], wb = mw[2*q + 1];
      float m0 = __uint_as_float(wa << 16);
      float m1 = __uint_as_float(wa & 0xffff0000u);
      float m2 = __uint_as_float(wb << 16);
      float m3 = __uint_as_float(wb & 0xffff0000u);
      p[4*q+0] = fexp2(fmaf(sacc[4*q+0], m0, -cc.x));
      p[4*q+1] = fexp2(fmaf(sacc[4*q+1], m1, -cc.y));
      p[4*q+2] = fexp2(fmaf(sacc[4*q+2], m2, -cc.z));
      p[4*q+3] = fexp2(fmaf(sacc[4*q+3], m3, -cc.w));
    }
    unsigned pu[8];
#pragma unroll
    for (int k = 0; k < 8; k++) pu[k] = cvtpk(p[2*k], p[2*k+1]);

    asm volatile("v_permlane32_swap_b32 %0, %1" : "+v"(pu[0]), "+v"(pu[2]));
    asm volatile("v_permlane32_swap_b32 %0, %1" : "+v"(pu[1]), "+v"(pu[3]));
    asm volatile("v_permlane32_swap_b32 %0, %1" : "+v"(pu[4]), "+v"(pu[6]));
    asm volatile("v_permlane32_swap_b32 %0, %1" : "+v"(pu[5]), "+v"(pu[7]));

    W4 PA0, PA1;
    PA0.u[0] = pu[0]; PA0.u[1] = pu[1]; PA0.u[2] = pu[2]; PA0.u[3] = pu[3];
    PA1.u[0] = pu[4]; PA1.u[1] = pu[5]; PA1.u[2] = pu[6]; PA1.u[3] = pu[7];

    oacc = __builtin_amdgcn_mfma_f32_32x32x16_bf16(PA0.v, vb1, oacc, 0, 0, 0);
    oacc = __builtin_amdgcn_mfma_f32_32x32x16_bf16(PA1.v, vb2, oacc, 0, 0, 0);
    oacc = __builtin_amdgcn_mfma_f32_32x32x16_bf16(A0c.v, hb1, oacc, 0, 0, 0);
    oacc = __builtin_amdgcn_mfma_f32_32x32x16_bf16(A1c.v, hb2, oacc, 0, 0, 0);

    if (t < 15) {
      A0c = A0n; A1c = A1n;
      for (int m = 0; m < 4; m++) kac[m] = kan[m];
    }
  }

  float* obase = opart + (size_t)slice*OSZ;
#pragma unroll
  for (int r = 0; r < 16; r++) {
    int orow = i0 + iq*32 + (r&3) + 8*(r>>2) + 4*h;
    int ocol = dh*32 + l31;
    obase[(size_t)orow*64 + ocol] = oacc[r];
  }
}

// ---------------------------------------------------------------------------
// reduce: out = sum over 16 slices of opart  (float4, fully coalesced)
// ---------------------------------------------------------------------------
__global__ __launch_bounds__(256) void reduce_kernel(
    const float* __restrict__ opart, float* __restrict__ out)
{
  int e4 = blockIdx.x * blockDim.x + threadIdx.x;   // 0..131071
  const float4* p = (const float4*)opart;
  float4 a = p[e4];
#pragma unroll
  for (int s = 1; s < 16; s++) {
    float4 b = p[(size_t)s*(OSZ/4) + e4];
    a.x += b.x; a.y += b.y; a.z += b.z; a.w += b.w;
  }
  ((float4*)out)[e4] = a;
}

// ---------------------------------------------------------------------------
extern "C" void kernel_launch(void* const* d_in, const int* in_sizes, int n_in,
                              void* d_out, int out_size, void* d_ws, size_t ws_size,
                              hipStream_t stream) {
  const float* X   = (const float*)d_in[0];
  const float* H   = (const float*)d_in[1];
  const float* M   = (const float*)d_in[2];
  const float* Qw  = (const float*)d_in[3];
  const float* Qb  = (const float*)d_in[4];
  const float* Kw  = (const float*)d_in[5];
  const float* Kb  = (const float*)d_in[6];
  const float* Vw  = (const float*)d_in[7];
  const float* Vb  = (const float*)d_in[8];
  const float* bng = (const float*)d_in[9];
  const float* bnb = (const float*)d_in[10];
  const float* bnm = (const float*)d_in[11];
  const float* bnv = (const float*)d_in[12];
  float* out = (float*)d_out;

  char* ws = (char*)d_ws;
  const size_t MB = 1024*1024;
  unsigned* MT4       = (unsigned*)(ws);                 // 128 MB
  unsigned short* QP  = (unsigned short*)(ws + 128*MB);  // 1 MB
  unsigned short* KP  = (unsigned short*)(ws + 129*MB);
  unsigned short* VP  = (unsigned short*)(ws + 130*MB);
  unsigned short* HP  = (unsigned short*)(ws + 131*MB);
  float* pd           = (float*)(ws + 132*MB);           // 1 MB
  float* colcc        = (float*)(ws + 133*MB);           // 32 KB
  float* opart        = (float*)(ws + 134*MB);           // 32 MB

  qkv_kernel<<<512, 256, 0, stream>>>(X, H, Qw, Qb, Kw, Kb, Vw, Vb,
                                      bng, bnb, bnm, bnv, QP, KP, VP, HP);
  pass1_kernel<<<2048, 256, 0, stream>>>(M, QP, KP, MT4, pd);
  combine_kernel<<<32, 256, 0, stream>>>(pd, colcc);
  pass2_kernel<<<2048, 256, 0, stream>>>(MT4, QP, KP, VP, HP, colcc, opart);
  reduce_kernel<<<512, 256, 0, stream>>>(opart, out);
}